// Round 1
// baseline (879.675 us; speedup 1.0000x reference)
//
#include <hip/hip_runtime.h>

#define BB 256
#define TT 2048
#define KK 64
#define NWAVE 8
#define PP 8            // p-values per wave (NWAVE*PP == KK)
#define CHUNK 64
#define NCHUNK (TT / CHUNK)   // 32
#define NEG_INF_F (-10000.0f)

__global__ __launch_bounds__(512, 2)
void viterbi_fwd_bt(const float* __restrict__ feats,
                    const float* __restrict__ trans,
                    const int* __restrict__ start_tag_p,
                    const int* __restrict__ stop_tag_p,
                    float* __restrict__ out,
                    unsigned char* __restrict__ bp_ws)
{
    const int b    = blockIdx.x;
    const int tid  = threadIdx.x;
    const int lane = tid & 63;
    const int wraw = tid >> 6;
    const int w    = __builtin_amdgcn_readfirstlane(wraw);  // wave-uniform
    const int n    = lane;

    const int start_tag = *start_tag_p;
    const int stop_tag  = *stop_tag_p;

    __shared__ float2 part[2][NWAVE][KK];   // (best, idx-bits) partials, double buffered
    __shared__ int    cmap[NCHUNK][KK];     // composed backpointer maps per chunk
    __shared__ float  term_lds[KK];
    __shared__ int    be_lds[NCHUNK];
    __shared__ int    bl_lds;

    const float* fb = feats + (size_t)b * TT * KK;
    unsigned char* bpb = bp_ws + (size_t)b * TT * KK;

    // preload transition fragments: lane n needs trans[n][w*PP + i]
    float tr[PP];
#pragma unroll
    for (int i = 0; i < PP; ++i)
        tr[i] = trans[n * KK + (w * PP + i)];
    const float tstop = trans[stop_tag * KK + n];

    float fv = (n == start_tag) ? 0.0f : NEG_INF_F;
    int   M  = n;   // composed map (wave 0 meaningful)

    // feat prefetch ring (depth 4), statically indexed
    float r0 = fb[0 * KK + n];
    float r1 = fb[1 * KK + n];
    float r2 = fb[2 * KK + n];
    float r3 = fb[3 * KK + n];

    auto step = [&](int t, float featval) {
        // ---- partial max/argmax over this wave's 8 p's (p ascending, strict >) ----
        float best = -3.0e38f;
        int   bidx = 0;
        const int fvbits = __float_as_int(fv);
#pragma unroll
        for (int i = 0; i < PP; ++i) {
            const int p = w * PP + i;
            const float fvp = __int_as_float(__builtin_amdgcn_readlane(fvbits, p));
            const float val = fvp + tr[i];
            const bool gt = val > best;
            bidx = gt ? p : bidx;
            best = fmaxf(best, val);
        }
        part[t & 1][w][n] = make_float2(best, __int_as_float(bidx));
        __syncthreads();

        // ---- combine 8 partials (w ascending keeps first-max tie-break) ----
        float2 p0 = part[t & 1][0][n];
        float bv = p0.x;
        int   bi = __float_as_int(p0.y);
#pragma unroll
        for (int wj = 1; wj < NWAVE; ++wj) {
            float2 pj = part[t & 1][wj][n];
            const bool gt = pj.x > bv;
            bi = gt ? __float_as_int(pj.y) : bi;
            bv = fmaxf(bv, pj.x);
        }
        const float fvnew = bv + featval;

        if (w == 0) {
            bpb[t * KK + n] = (unsigned char)bi;          // 64B coalesced store
            M = __shfl(M, bi);                            // M_new[j] = M_old[bp[j]]
            if ((t & (CHUNK - 1)) == (CHUNK - 1)) {
                cmap[t / CHUNK][n] = M;
                M = n;
            }
        }
        fv = fvnew;
    };

    for (int t = 0; t < TT; t += 4) {
        // issue prefetch early, consume ring slot at the end of each substep
        float nr0 = fb[((t + 4 < TT) ? (t + 4) : (TT - 1)) * KK + n];
        step(t + 0, r0); r0 = nr0;
        float nr1 = fb[((t + 5 < TT) ? (t + 5) : (TT - 1)) * KK + n];
        step(t + 1, r1); r1 = nr1;
        float nr2 = fb[((t + 6 < TT) ? (t + 6) : (TT - 1)) * KK + n];
        step(t + 2, r2); r2 = nr2;
        float nr3 = fb[((t + 7 < TT) ? (t + 7) : (TT - 1)) * KK + n];
        step(t + 3, r3); r3 = nr3;
    }

    // ---- terminal ----
    const float term = fv + tstop;
    if (w == 0) term_lds[n] = term;
    __syncthreads();
    if (tid == 0) {
        float bv = term_lds[0];
        int bi = 0;
        for (int j = 1; j < KK; ++j) {
            float v = term_lds[j];
            if (v > bv) { bv = v; bi = j; }
        }
        out[b] = bv;          // path_score
        bl_lds = bi;
    }
    __syncthreads();

    // ---- phase B: chunk-boundary tags via composed maps (serial, 32 LDS hops) ----
    if (tid == 0) {
        int x = bl_lds;
        be_lds[NCHUNK - 1] = x;
        for (int c = NCHUNK - 1; c >= 1; --c) {
            x = cmap[c][x];
            be_lds[c - 1] = x;
        }
    }
    __syncthreads();

    // ---- phase C: parallel interior walks (32 chunks in parallel) ----
    if (tid < NCHUNK) {
        const int c = tid;
        int x = be_lds[c];
        float* po = out + gridDim.x + (size_t)b * TT;   // path output base
        for (int t = (c + 1) * CHUNK - 1; t >= c * CHUNK; --t) {
            po[t] = (float)x;
            x = (int)bpb[t * KK + x];
        }
    }
}

extern "C" void kernel_launch(void* const* d_in, const int* in_sizes, int n_in,
                              void* d_out, int out_size, void* d_ws, size_t ws_size,
                              hipStream_t stream) {
    const float* feats = (const float*)d_in[0];
    const float* trans = (const float*)d_in[1];
    const int* start_tag = (const int*)d_in[2];
    const int* stop_tag  = (const int*)d_in[3];
    float* out = (float*)d_out;
    unsigned char* bp = (unsigned char*)d_ws;   // needs B*T*K = 33.5 MB

    viterbi_fwd_bt<<<BB, 512, 0, stream>>>(feats, trans, start_tag, stop_tag, out, bp);
}

// Round 2
// 604.853 us; speedup vs baseline: 1.4544x; 1.4544x over previous
//
#include <hip/hip_runtime.h>

#define BB 256
#define TT 2048
#define KK 64
#define CHUNK 64
#define NCHUNK (TT / CHUNK)   // 32
#define NEG_INF_F (-10000.0f)

// DPP cross-lane helpers (free VALU permutes within 16-lane rows)
#define DPP_XOR1 0xB1   // quad_perm [1,0,3,2]
#define DPP_XOR2 0x4E   // quad_perm [2,3,0,1]
#define DPP_HMIR 0x141  // row_half_mirror (== xor4 once quads are reduced)

template <int CTRL>
__device__ __forceinline__ float dpp_f(float x) {
    return __int_as_float(__builtin_amdgcn_update_dpp(
        0, __float_as_int(x), CTRL, 0xF, 0xF, true));
}
template <int CTRL>
__device__ __forceinline__ int dpp_i(int x) {
    return __builtin_amdgcn_update_dpp(0, x, CTRL, 0xF, 0xF, true);
}

__global__ __launch_bounds__(512, 2)
void viterbi_fwd_bt(const float* __restrict__ feats,
                    const float* __restrict__ trans,
                    const int* __restrict__ start_tag_p,
                    const int* __restrict__ stop_tag_p,
                    float* __restrict__ out,
                    unsigned char* __restrict__ bp_ws)
{
    const int b    = blockIdx.x;
    const int tid  = threadIdx.x;
    const int lane = tid & 63;
    const int w    = __builtin_amdgcn_readfirstlane(tid >> 6);  // wave id 0..7
    const int g    = lane >> 3;        // output-row group within wave
    const int j    = lane & 7;         // p-chunk within row
    const int n    = w * 8 + g;        // owned output row
    const int pbase = j * 8;           // first p of this lane's chunk

    const int start_tag = *start_tag_p;
    const int stop_tag  = *stop_tag_p;

    __shared__ float fv_lds[2][KK];    // double-buffered Viterbi variables
    __shared__ int   bp_lds[2][KK];    // double-buffered backpointer row
    __shared__ int   cmap[NCHUNK][KK]; // composed backpointer maps per chunk
    __shared__ float term_lds[KK];
    __shared__ int   be_lds[NCHUNK];

    const float* fb = feats + (size_t)b * TT * KK;
    unsigned char* bpb = bp_ws + (size_t)b * TT * KK;

    // per-lane transition fragment: trans[n][pbase + i]
    float tr[8];
#pragma unroll
    for (int i = 0; i < 8; ++i) tr[i] = trans[n * KK + pbase + i];
    const float tstop = trans[stop_tag * KK + lane];

    // p-index constants in VGPRs for the cndmask chain
    int p0 = pbase + 0, p1 = pbase + 1, p2 = pbase + 2, p3 = pbase + 3;
    int p4 = pbase + 4, p5 = pbase + 5, p6 = pbase + 6, p7 = pbase + 7;

    if (tid < KK) fv_lds[0][tid] = (tid == start_tag) ? 0.0f : NEG_INF_F;
    int M = lane;   // composed map (wave 0 only meaningful)
    __syncthreads();

    // feat prefetch ring (depth 4); only value for row n is needed
    float r0 = fb[0 * KK + n];
    float r1 = fb[1 * KK + n];
    float r2 = fb[2 * KK + n];
    float r3 = fb[3 * KK + n];

    auto step = [&](int t, float featval) {
        // ---- read fv fragment (8-fold broadcast addresses, conflict-free) ----
        const float4* fp = (const float4*)&fv_lds[t & 1][pbase];
        const float4 fa = fp[0];
        const float4 fc = fp[1];

        // ---- wave 0: lagged composed-map update for step t-1 ----
        if (w == 0 && t > 0) {
            const int bp = bp_lds[(t + 1) & 1][lane];       // (t-1)&1
            bpb[(size_t)(t - 1) * KK + lane] = (unsigned char)bp;  // 64B coalesced
            M = __shfl(M, bp);                              // M_new[q] = M_old[bp[q]]
            if (((t - 1) & (CHUNK - 1)) == (CHUNK - 1)) {
                cmap[(t - 1) >> 6][lane] = M;
                M = lane;
            }
        }

        // ---- scores for this lane's 8 p's ----
        const float v0 = fa.x + tr[0], v1 = fa.y + tr[1];
        const float v2 = fa.z + tr[2], v3 = fa.w + tr[3];
        const float v4 = fc.x + tr[4], v5 = fc.y + tr[5];
        const float v6 = fc.z + tr[6], v7 = fc.w + tr[7];

        // in-lane max tree
        float m = fmaxf(fmaxf(fmaxf(v0, v1), fmaxf(v2, v3)),
                        fmaxf(fmaxf(v4, v5), fmaxf(v6, v7)));
        // cross-lane max over the 8 lanes sharing row n (free DPP)
        m = fmaxf(m, dpp_f<DPP_XOR1>(m));
        m = fmaxf(m, dpp_f<DPP_XOR2>(m));
        m = fmaxf(m, dpp_f<DPP_HMIR>(m));

        // equality scan: candidate = smallest matching p in this lane
        int idx = 0x3FFFFFFF;
        idx = (v7 == m) ? p7 : idx;
        idx = (v6 == m) ? p6 : idx;
        idx = (v5 == m) ? p5 : idx;
        idx = (v4 == m) ? p4 : idx;
        idx = (v3 == m) ? p3 : idx;
        idx = (v2 == m) ? p2 : idx;
        idx = (v1 == m) ? p1 : idx;
        idx = (v0 == m) ? p0 : idx;
        // cross-lane min -> global argmax (first-max tie-break preserved)
        idx = min(idx, dpp_i<DPP_XOR1>(idx));
        idx = min(idx, dpp_i<DPP_XOR2>(idx));
        idx = min(idx, dpp_i<DPP_HMIR>(idx));

        if (j == 0) {
            fv_lds[(t + 1) & 1][n] = m + featval;   // consecutive addrs, no conflict
            bp_lds[t & 1][n] = idx;
        }
        __syncthreads();
    };

    for (int t = 0; t < TT; t += 4) {
        float nr0 = fb[((t + 4 < TT) ? (t + 4) : (TT - 1)) * KK + n];
        step(t + 0, r0); r0 = nr0;
        float nr1 = fb[((t + 5 < TT) ? (t + 5) : (TT - 1)) * KK + n];
        step(t + 1, r1); r1 = nr1;
        float nr2 = fb[((t + 6 < TT) ? (t + 6) : (TT - 1)) * KK + n];
        step(t + 2, r2); r2 = nr2;
        float nr3 = fb[((t + 7 < TT) ? (t + 7) : (TT - 1)) * KK + n];
        step(t + 3, r3); r3 = nr3;
    }

    // ---- final lagged update (t = TT-1) + terminal scores ----
    if (w == 0) {
        const int bp = bp_lds[(TT - 1) & 1][lane];
        bpb[(size_t)(TT - 1) * KK + lane] = (unsigned char)bp;
        M = __shfl(M, bp);
        cmap[NCHUNK - 1][lane] = M;
        term_lds[lane] = fv_lds[TT & 1][lane] + tstop;
    }
    __syncthreads();

    // ---- terminal argmax + chunk-boundary tags (serial, once) ----
    if (tid == 0) {
        float bv = term_lds[0];
        int bi = 0;
        for (int k = 1; k < KK; ++k) {
            const float vv = term_lds[k];
            if (vv > bv) { bv = vv; bi = k; }
        }
        out[b] = bv;                 // path_score
        int x = bi;
        be_lds[NCHUNK - 1] = x;
        for (int c = NCHUNK - 1; c >= 1; --c) {
            x = cmap[c][x];
            be_lds[c - 1] = x;
        }
    }
    __syncthreads();

    // ---- parallel interior backtrace (32 chunks) ----
    if (tid < NCHUNK) {
        const int c = tid;
        int x = be_lds[c];
        float* po = out + BB + (size_t)b * TT;
        for (int t = (c + 1) * CHUNK - 1; t >= c * CHUNK; --t) {
            po[t] = (float)x;
            x = (int)bpb[(size_t)t * KK + x];
        }
    }
}

extern "C" void kernel_launch(void* const* d_in, const int* in_sizes, int n_in,
                              void* d_out, int out_size, void* d_ws, size_t ws_size,
                              hipStream_t stream) {
    const float* feats = (const float*)d_in[0];
    const float* trans = (const float*)d_in[1];
    const int* start_tag = (const int*)d_in[2];
    const int* stop_tag  = (const int*)d_in[3];
    float* out = (float*)d_out;
    unsigned char* bp = (unsigned char*)d_ws;   // B*T*K = 33.5 MB backpointers

    viterbi_fwd_bt<<<BB, 512, 0, stream>>>(feats, trans, start_tag, stop_tag, out, bp);
}